// Round 2
// baseline (706.040 us; speedup 1.0000x reference)
//
#include <hip/hip_runtime.h>
#include <hip/hip_bf16.h>

// ---------------------------------------------------------------------------
// TransformerBlock fused pipeline for MI355X (gfx950).
// x:[4,2048,1024] f32. Residual stream fp32; GEMM/attn compute bf16 MFMA.
// Stages:
//   1) transpose-convert weights f32[K,N] -> bf16[N,K] (QKV packed [3072,1024])
//   2) rmsnorm(x,g1) -> bf16 xn
//   3) QKV = xn @ Wqkv            (gemm_bt MODE 0, bf16 out)
//   4) flash attention            (bf16 out)
//   5) x1 = attn @ Wo + x         (MODE 1, fp32 -> d_out)
//   6) rmsnorm(x1,g2) -> bf16 xn
//   7) h  = gelu(xn @ W1)         (MODE 2, bf16 out)
//   8) out = h @ W2 + x1          (MODE 3, fp32 -> d_out, in-place safe)
// ---------------------------------------------------------------------------

typedef __attribute__((ext_vector_type(8))) short bf16x8;    // MFMA A/B frag
typedef __attribute__((ext_vector_type(4))) float f32x4;     // MFMA C/D frag
typedef __attribute__((ext_vector_type(8))) unsigned short u16x8;
typedef __attribute__((ext_vector_type(4))) unsigned short u16x4;

#define DEV static __device__ __forceinline__

DEV unsigned short f2b(float f){
  __hip_bfloat16 h = __float2bfloat16(f);
  union { __hip_bfloat16 h; unsigned short u; } cv; cv.h = h; return cv.u;
}

// async global->LDS, 16B per lane. LDS dest is wave-uniform base; HW adds lane*16.
DEV void async16(const void* g, void* l){
  __builtin_amdgcn_global_load_lds((__attribute__((address_space(1))) void*)(void*)g,
                                   (__attribute__((address_space(3))) void*)l, 16, 0, 0);
}

// ---------------- transpose + f32->bf16 convert: in[R][C] -> out[C][R] -----
__global__ __launch_bounds__(256) void transpose_bf16(
    const float* __restrict__ in, unsigned short* __restrict__ out, int R, int C)
{
  __shared__ float tile[32][33];
  int c0 = blockIdx.x * 32, r0 = blockIdx.y * 32;
  int tx = threadIdx.x & 31, ty = threadIdx.x >> 5;   // 32 x 8
#pragma unroll
  for (int i = 0; i < 4; i++)
    tile[ty + 8*i][tx] = in[(size_t)(r0 + ty + 8*i) * C + c0 + tx];
  __syncthreads();
#pragma unroll
  for (int i = 0; i < 4; i++)
    out[(size_t)(c0 + ty + 8*i) * R + r0 + tx] = f2b(tile[tx][ty + 8*i]);
}

// ---------------- RMSNorm: f32[row][1024] -> bf16, one block per row -------
__global__ __launch_bounds__(256) void rmsnorm_k(
    const float* __restrict__ x, const float* __restrict__ g,
    unsigned short* __restrict__ out)
{
  int row = blockIdx.x, t = threadIdx.x;
  const float4* xr = (const float4*)(x + (size_t)row * 1024);
  float4 v = xr[t];
  float ss = v.x*v.x + v.y*v.y + v.z*v.z + v.w*v.w;
#pragma unroll
  for (int o = 32; o > 0; o >>= 1) ss += __shfl_xor(ss, o, 64);
  __shared__ float wsum[4];
  int lane = t & 63, wv = t >> 6;
  if (lane == 0) wsum[wv] = ss;
  __syncthreads();
  float inv = rsqrtf((wsum[0]+wsum[1]+wsum[2]+wsum[3]) * (1.0f/1024.0f) + 1e-5f);
  float4 gv = ((const float4*)g)[t];
  u16x4 o;
  o[0] = f2b(v.x * inv * gv.x);
  o[1] = f2b(v.y * inv * gv.y);
  o[2] = f2b(v.z * inv * gv.z);
  o[3] = f2b(v.w * inv * gv.w);
  *(u16x4*)(out + (size_t)row * 1024 + t * 4) = o;
}

// ---------------- GEMM: C[M,N] = A[M,K](bf16) @ Bt[N,K](bf16)^T ------------
// 128x128 tile, BK=64, 4 waves (2x2), each wave 64x64 = 4x4 mfma 16x16x32.
// LDS XOR-swizzled (slot ^= row&7) via pre-swizzled global source (rule 21).
// MODE: 0 = bf16 store; 1 = f32 +resid; 2 = gelu->bf16; 3 = f32 +resid.
template<int MODE>
__global__ __launch_bounds__(256) void gemm_bt(
    const unsigned short* __restrict__ A,
    const unsigned short* __restrict__ Bt,
    const float* __restrict__ resid,
    float* __restrict__ outF,
    unsigned short* __restrict__ outB,
    int N, int K)
{
  __shared__ __attribute__((aligned(16))) unsigned short lA[128*64];
  __shared__ __attribute__((aligned(16))) unsigned short lB[128*64];

  const int nTn = N >> 7;
  const int nwg = gridDim.x;                       // all grids %8 == 0
  int wg = ((int)blockIdx.x & 7) * (nwg >> 3) + ((int)blockIdx.x >> 3);
  const int tm = wg / nTn, tn = wg % nTn;
  const int tid = threadIdx.x;
  const int lane = tid & 63, w = tid >> 6;
  const int r15 = lane & 15, hi = lane >> 4;
  const int wm = (w >> 1) << 6, wn = (w & 1) << 6;

  f32x4 acc[4][4];
#pragma unroll
  for (int i = 0; i < 4; i++)
#pragma unroll
    for (int j = 0; j < 4; j++) acc[i][j] = f32x4{0.f, 0.f, 0.f, 0.f};

  const size_t arow0 = (size_t)tm * 128;
  const size_t brow0 = (size_t)tn * 128;

  for (int k0 = 0; k0 < K; k0 += 64) {
    __syncthreads();                                // prev-tile readers done
#pragma unroll
    for (int i = 0; i < 4; i++) {                   // stage A: 16KB
      int s = (i*4 + w) * 64 + lane;
      int row = s >> 3, sl = s & 7;
      int col = (sl ^ (row & 7)) << 3;              // inverse-swizzled source
      async16(A + (arow0 + row) * K + k0 + col, (char*)lA + (size_t)(i*4 + w) * 1024);
    }
#pragma unroll
    for (int i = 0; i < 4; i++) {                   // stage B: 16KB
      int s = (i*4 + w) * 64 + lane;
      int row = s >> 3, sl = s & 7;
      int col = (sl ^ (row & 7)) << 3;
      async16(Bt + (brow0 + row) * K + k0 + col, (char*)lB + (size_t)(i*4 + w) * 1024);
    }
    __syncthreads();                                // vmcnt drained by compiler

#pragma unroll
    for (int kc = 0; kc < 2; kc++) {
      bf16x8 af[4], bfr[4];
#pragma unroll
      for (int mi = 0; mi < 4; mi++) {
        int row = wm + mi*16 + r15;
        int esl = (kc*4 + hi) ^ (row & 7);          // swizzled read
        af[mi] = *(const bf16x8*)&lA[row*64 + esl*8];
      }
#pragma unroll
      for (int ni = 0; ni < 4; ni++) {
        int row = wn + ni*16 + r15;
        int esl = (kc*4 + hi) ^ (row & 7);
        bfr[ni] = *(const bf16x8*)&lB[row*64 + esl*8];
      }
#pragma unroll
      for (int mi = 0; mi < 4; mi++)
#pragma unroll
        for (int ni = 0; ni < 4; ni++)
          acc[mi][ni] = __builtin_amdgcn_mfma_f32_16x16x32_bf16(
              af[mi], bfr[ni], acc[mi][ni], 0, 0, 0);
    }
  }

  // epilogue: C/D layout col=lane&15, row=(lane>>4)*4+reg (m89/m91 verified)
#pragma unroll
  for (int mi = 0; mi < 4; mi++) {
#pragma unroll
    for (int ni = 0; ni < 4; ni++) {
#pragma unroll
      for (int r = 0; r < 4; r++) {
        size_t row = arow0 + wm + mi*16 + hi*4 + r;
        size_t col = brow0 + wn + ni*16 + r15;
        size_t idx = row * (size_t)N + col;
        float v = acc[mi][ni][r];
        if (MODE == 0)      outB[idx] = f2b(v);
        else if (MODE == 1) outF[idx] = v + resid[idx];
        else if (MODE == 2) outB[idx] = f2b(0.5f * v * (1.0f + erff(v * 0.70710678118654752f)));
        else                outF[idx] = v + resid[idx];
      }
    }
  }
}

// ---------------- Flash attention (causal), bf16 -----------------------------
// QKV[b*2048+t][3072]: Q at col h*64, K at 1024+h*64, V at 2048+h*64.
// Block: 64 q-rows (4 waves x 16), KBLK=32. Online softmax per q-row across
// the 16 lanes holding its tokens (shfl_xor 1/2/4/8). P via LDS round-trip.
__global__ __launch_bounds__(256) void attn_k(
    const unsigned short* __restrict__ QKV, unsigned short* __restrict__ outB)
{
  const int nwg = gridDim.x;                       // 2048
  int logical = ((int)blockIdx.x & 7) * (nwg >> 3) + ((int)blockIdx.x >> 3);
  int qt = logical & 31, bh = logical >> 5;
  int b = bh >> 4, h = bh & 15;
  const int tid = threadIdx.x, lane = tid & 63, w = tid >> 6;
  const int r15 = lane & 15, hi = lane >> 4;
  const int LD = 3072;
  const size_t rowbase = (size_t)b * 2048;
  const int q0 = qt * 64;
  const int qw = q0 + w * 16;                      // wave strip start

  // Q fragments in registers (row = r15, d = kc*32 + hi*8 + j)
  bf16x8 aq[2];
  {
    const unsigned short* qp = QKV + (rowbase + q0 + w*16 + r15) * LD + h * 64;
    aq[0] = *(const bf16x8*)(qp + hi * 8);
    aq[1] = *(const bf16x8*)(qp + 32 + hi * 8);
  }

  __shared__ __attribute__((aligned(16))) unsigned short lK[32 * 64];
  __shared__ __attribute__((aligned(16))) unsigned short lVt[64 * 32];
  __shared__ __attribute__((aligned(16))) unsigned short lP[4][16 * 32];

  f32x4 y[4];
#pragma unroll
  for (int db = 0; db < 4; db++) y[db] = f32x4{0.f, 0.f, 0.f, 0.f};
  float mrow[4] = {-1e30f, -1e30f, -1e30f, -1e30f};
  float lrow[4] = {0.f, 0.f, 0.f, 0.f};

  const int ktmax_w = (qw + 15) >> 5;              // last tile this wave needs
  const int nkt = (q0 >> 5) + 2;                   // block-uniform loop bound

  for (int kt = 0; kt < nkt; kt++) {
    __syncthreads();                               // protect LDS reuse
    {                                              // stage K and V^T tiles
      int row = tid >> 3, ch = tid & 7;            // tok row 0..31, 16B chunk
      const unsigned short* kp = QKV + (rowbase + kt*32 + row) * LD + 1024 + h*64 + ch*8;
      *(u16x8*)&lK[row*64 + ch*8] = *(const u16x8*)kp;
      const unsigned short* vp = QKV + (rowbase + kt*32 + row) * LD + 2048 + h*64 + ch*8;
      u16x8 vv = *(const u16x8*)vp;
#pragma unroll
      for (int j = 0; j < 8; j++) lVt[(ch*8 + j)*32 + row] = vv[j];
    }
    __syncthreads();

    if (kt <= ktmax_w) {
      // S = Q K^T  (S[q][tok]: col=tok=r15(+tb*16), row=q=hi*4+r)
      f32x4 s[2] = { f32x4{0.f,0.f,0.f,0.f}, f32x4{0.f,0.f,0.f,0.f} };
#pragma unroll
      for (int tb = 0; tb < 2; tb++)
#pragma unroll
        for (int kc = 0; kc < 2; kc++) {
          bf16x8 kf = *(const bf16x8*)&lK[(tb*16 + r15)*64 + kc*32 + hi*8];
          s[tb] = __builtin_amdgcn_mfma_f32_16x16x32_bf16(aq[kc], kf, s[tb], 0, 0, 0);
        }

      const bool needmask = (kt*32 + 31 > qw);
      float alpha[4];
#pragma unroll
      for (int r = 0; r < 4; r++) {
        int q = qw + hi*4 + r;
        float s0 = s[0][r] * 0.125f, s1 = s[1][r] * 0.125f;
        if (needmask) {
          int t0 = kt*32 + r15;
          if (t0 > q)      s0 = -1e30f;
          if (t0 + 16 > q) s1 = -1e30f;
        }
        float mx = fmaxf(s0, s1);
        mx = fmaxf(mx, __shfl_xor(mx, 1, 64));
        mx = fmaxf(mx, __shfl_xor(mx, 2, 64));
        mx = fmaxf(mx, __shfl_xor(mx, 4, 64));
        mx = fmaxf(mx, __shfl_xor(mx, 8, 64));
        float mnew = fmaxf(mrow[r], mx);
        float p0 = __expf(s0 - mnew), p1 = __expf(s1 - mnew);
        float al = __expf(mrow[r] - mnew);
        float rs = p0 + p1;
        rs += __shfl_xor(rs, 1, 64);
        rs += __shfl_xor(rs, 2, 64);
        rs += __shfl_xor(rs, 4, 64);
        rs += __shfl_xor(rs, 8, 64);
        lrow[r] = lrow[r] * al + rs;
        mrow[r] = mnew;
        alpha[r] = al;
        lP[w][(hi*4 + r)*32 + r15]      = f2b(p0);
        lP[w][(hi*4 + r)*32 + 16 + r15] = f2b(p1);
      }
#pragma unroll
      for (int db = 0; db < 4; db++)
#pragma unroll
        for (int r = 0; r < 4; r++) y[db][r] *= alpha[r];

      asm volatile("s_waitcnt lgkmcnt(0)" ::: "memory");  // P writes visible
      __builtin_amdgcn_sched_barrier(0);

      // y += P V  (A=P: row=q=r15, k=tok=hi*8+j; B=V: col=d, k=tok from lVt)
      bf16x8 pf = *(const bf16x8*)&lP[w][r15*32 + hi*8];
#pragma unroll
      for (int db = 0; db < 4; db++) {
        bf16x8 vf = *(const bf16x8*)&lVt[(db*16 + r15)*32 + hi*8];
        y[db] = __builtin_amdgcn_mfma_f32_16x16x32_bf16(pf, vf, y[db], 0, 0, 0);
      }
    }
  }

#pragma unroll
  for (int r = 0; r < 4; r++) {
    float inv = 1.0f / lrow[r];
    size_t row = rowbase + q0 + w*16 + hi*4 + r;
#pragma unroll
    for (int db = 0; db < 4; db++)
      outB[row * 1024 + h*64 + db*16 + r15] = f2b(y[db][r] * inv);
  }
}

// ---------------------------------------------------------------------------
extern "C" void kernel_launch(void* const* d_in, const int* in_sizes, int n_in,
                              void* d_out, int out_size, void* d_ws, size_t ws_size,
                              hipStream_t stream) {
  const float* x  = (const float*)d_in[0];
  const float* Wq = (const float*)d_in[1];
  const float* Wk = (const float*)d_in[2];
  const float* Wv = (const float*)d_in[3];
  const float* Wo = (const float*)d_in[4];
  const float* W1 = (const float*)d_in[5];
  const float* W2 = (const float*)d_in[6];
  const float* g1 = (const float*)d_in[7];
  const float* g2 = (const float*)d_in[8];
  float* out = (float*)d_out;                      // fp32 output; also holds x1

  // ws layout (bf16 elems): Wqkv_t[3072*1024] Wo_t[1M] W1_t[4M] W2_t[4M]
  //                         xn[8M] attno[8M] qkv[24M]; hff reuses attno+qkv.
  unsigned short* wQKVt = (unsigned short*)d_ws;
  unsigned short* wOt   = wQKVt + (size_t)3072 * 1024;
  unsigned short* w1t   = wOt   + (size_t)1024 * 1024;
  unsigned short* w2t   = w1t   + (size_t)4096 * 1024;
  unsigned short* xn    = w2t   + (size_t)1024 * 4096;
  unsigned short* attno = xn    + (size_t)8192 * 1024;
  unsigned short* qkv   = attno + (size_t)8192 * 1024;
  unsigned short* hff   = attno;                   // [8192,4096] after attn/proj

  transpose_bf16<<<dim3(32, 32),  256, 0, stream>>>(Wq, wQKVt,                     1024, 1024);
  transpose_bf16<<<dim3(32, 32),  256, 0, stream>>>(Wk, wQKVt + (size_t)1024*1024, 1024, 1024);
  transpose_bf16<<<dim3(32, 32),  256, 0, stream>>>(Wv, wQKVt + (size_t)2048*1024, 1024, 1024);
  transpose_bf16<<<dim3(32, 32),  256, 0, stream>>>(Wo, wOt,                       1024, 1024);
  transpose_bf16<<<dim3(128, 32), 256, 0, stream>>>(W1, w1t,                       1024, 4096);
  transpose_bf16<<<dim3(32, 128), 256, 0, stream>>>(W2, w2t,                       4096, 1024);

  rmsnorm_k<<<8192, 256, 0, stream>>>(x, g1, xn);
  gemm_bt<0><<<64 * 24, 256, 0, stream>>>(xn, wQKVt, nullptr, nullptr, qkv, 3072, 1024);
  attn_k<<<2048, 256, 0, stream>>>(qkv, attno);
  gemm_bt<1><<<64 * 8, 256, 0, stream>>>(attno, wOt, x, out, nullptr, 1024, 1024);
  rmsnorm_k<<<8192, 256, 0, stream>>>(out, g2, xn);
  gemm_bt<2><<<64 * 32, 256, 0, stream>>>(xn, w1t, nullptr, nullptr, hff, 4096, 1024);
  gemm_bt<3><<<64 * 8, 256, 0, stream>>>(hff, w2t, out, out, nullptr, 1024, 4096);
}

// Round 5
// 667.962 us; speedup vs baseline: 1.0570x; 1.0570x over previous
//
#include <hip/hip_runtime.h>
#include <hip/hip_bf16.h>

// ---------------------------------------------------------------------------
// TransformerBlock fused pipeline for MI355X (gfx950).
// x:[4,2048,1024] f32. Residual stream fp32; GEMM/attn compute bf16 MFMA.
// Stages:
//   1) transpose-convert weights f32[K,N] -> bf16[N,K] (QKV packed [3072,1024])
//   2) rmsnorm(x,g1) -> bf16 xn
//   3) QKV = xn @ Wqkv            (gemm_bt MODE 0, bf16 out)
//   4) flash attention            (bf16 out)
//   5) x1 = attn @ Wo + x         (MODE 1, fp32 -> d_out)
//   6) rmsnorm(x1,g2) -> bf16 xn
//   7) h  = gelu(xn @ W1)         (MODE 2, bf16 out)
//   8) out = h @ W2 + x1          (MODE 3, fp32 -> d_out, in-place safe)
// ---------------------------------------------------------------------------

typedef __attribute__((ext_vector_type(8))) short bf16x8;    // MFMA A/B frag
typedef __attribute__((ext_vector_type(4))) float f32x4;     // MFMA C/D frag
typedef __attribute__((ext_vector_type(8))) unsigned short u16x8;
typedef __attribute__((ext_vector_type(4))) unsigned short u16x4;

#define DEV static __device__ __forceinline__

DEV unsigned short f2b(float f){
  __hip_bfloat16 h = __float2bfloat16(f);
  union { __hip_bfloat16 h; unsigned short u; } cv; cv.h = h; return cv.u;
}

// async global->LDS, 16B per lane. LDS dest is wave-uniform base; HW adds lane*16.
DEV void async16(const void* g, void* l){
  __builtin_amdgcn_global_load_lds((__attribute__((address_space(1))) void*)(void*)g,
                                   (__attribute__((address_space(3))) void*)l, 16, 0, 0);
}

// ---------------- transpose + f32->bf16 convert: in[R][C] -> out[C][R] -----
__global__ __launch_bounds__(256) void transpose_bf16(
    const float* __restrict__ in, unsigned short* __restrict__ out, int R, int C)
{
  __shared__ float tile[32][33];
  int c0 = blockIdx.x * 32, r0 = blockIdx.y * 32;
  int tx = threadIdx.x & 31, ty = threadIdx.x >> 5;   // 32 x 8
#pragma unroll
  for (int i = 0; i < 4; i++)
    tile[ty + 8*i][tx] = in[(size_t)(r0 + ty + 8*i) * C + c0 + tx];
  __syncthreads();
#pragma unroll
  for (int i = 0; i < 4; i++)
    out[(size_t)(c0 + ty + 8*i) * R + r0 + tx] = f2b(tile[tx][ty + 8*i]);
}

// ---------------- RMSNorm: f32[row][1024] -> bf16, one block per row -------
__global__ __launch_bounds__(256) void rmsnorm_k(
    const float* __restrict__ x, const float* __restrict__ g,
    unsigned short* __restrict__ out)
{
  int row = blockIdx.x, t = threadIdx.x;
  const float4* xr = (const float4*)(x + (size_t)row * 1024);
  float4 v = xr[t];
  float ss = v.x*v.x + v.y*v.y + v.z*v.z + v.w*v.w;
#pragma unroll
  for (int o = 32; o > 0; o >>= 1) ss += __shfl_xor(ss, o, 64);
  __shared__ float wsum[4];
  int lane = t & 63, wv = t >> 6;
  if (lane == 0) wsum[wv] = ss;
  __syncthreads();
  float inv = rsqrtf((wsum[0]+wsum[1]+wsum[2]+wsum[3]) * (1.0f/1024.0f) + 1e-5f);
  float4 gv = ((const float4*)g)[t];
  u16x4 o;
  o[0] = f2b(v.x * inv * gv.x);
  o[1] = f2b(v.y * inv * gv.y);
  o[2] = f2b(v.z * inv * gv.z);
  o[3] = f2b(v.w * inv * gv.w);
  *(u16x4*)(out + (size_t)row * 1024 + t * 4) = o;
}

// ---------------- GEMM: C[M,N] = A[M,K](bf16) @ Bt[N,K](bf16)^T ------------
// 128x128 tile, BK=64, 4 waves (2x2), each wave 64x64 = 4x4 mfma 16x16x32.
// LDS XOR-swizzled (slot ^= row&7) via pre-swizzled global source (rule 21).
// MODE: 0 = bf16 store; 1 = f32 +resid; 2 = gelu->bf16; 3 = f32 +resid.
template<int MODE>
__global__ __launch_bounds__(256) void gemm_bt(
    const unsigned short* __restrict__ A,
    const unsigned short* __restrict__ Bt,
    const float* __restrict__ resid,
    float* __restrict__ outF,
    unsigned short* __restrict__ outB,
    int N, int K)
{
  __shared__ __attribute__((aligned(16))) unsigned short lA[128*64];
  __shared__ __attribute__((aligned(16))) unsigned short lB[128*64];

  const int nTn = N >> 7;
  const int nwg = gridDim.x;                       // all grids %8 == 0
  int wg = ((int)blockIdx.x & 7) * (nwg >> 3) + ((int)blockIdx.x >> 3);
  const int tm = wg / nTn, tn = wg % nTn;
  const int tid = threadIdx.x;
  const int lane = tid & 63, w = tid >> 6;
  const int r15 = lane & 15, hi = lane >> 4;
  const int wm = (w >> 1) << 6, wn = (w & 1) << 6;

  f32x4 acc[4][4];
#pragma unroll
  for (int i = 0; i < 4; i++)
#pragma unroll
    for (int j = 0; j < 4; j++) acc[i][j] = f32x4{0.f, 0.f, 0.f, 0.f};

  const size_t arow0 = (size_t)tm * 128;
  const size_t brow0 = (size_t)tn * 128;

  for (int k0 = 0; k0 < K; k0 += 64) {
    __syncthreads();                                // prev-tile readers done
#pragma unroll
    for (int i = 0; i < 4; i++) {                   // stage A: 16KB
      int s = (i*4 + w) * 64 + lane;
      int row = s >> 3, sl = s & 7;
      int col = (sl ^ (row & 7)) << 3;              // inverse-swizzled source
      async16(A + (arow0 + row) * K + k0 + col, (char*)lA + (size_t)(i*4 + w) * 1024);
    }
#pragma unroll
    for (int i = 0; i < 4; i++) {                   // stage B: 16KB
      int s = (i*4 + w) * 64 + lane;
      int row = s >> 3, sl = s & 7;
      int col = (sl ^ (row & 7)) << 3;
      async16(Bt + (brow0 + row) * K + k0 + col, (char*)lB + (size_t)(i*4 + w) * 1024);
    }
    __syncthreads();                                // vmcnt drained by compiler

#pragma unroll
    for (int kc = 0; kc < 2; kc++) {
      bf16x8 af[4], bfr[4];
#pragma unroll
      for (int mi = 0; mi < 4; mi++) {
        int row = wm + mi*16 + r15;
        int esl = (kc*4 + hi) ^ (row & 7);          // swizzled read
        af[mi] = *(const bf16x8*)&lA[row*64 + esl*8];
      }
#pragma unroll
      for (int ni = 0; ni < 4; ni++) {
        int row = wn + ni*16 + r15;
        int esl = (kc*4 + hi) ^ (row & 7);
        bfr[ni] = *(const bf16x8*)&lB[row*64 + esl*8];
      }
#pragma unroll
      for (int mi = 0; mi < 4; mi++)
#pragma unroll
        for (int ni = 0; ni < 4; ni++)
          acc[mi][ni] = __builtin_amdgcn_mfma_f32_16x16x32_bf16(
              af[mi], bfr[ni], acc[mi][ni], 0, 0, 0);
    }
  }

  // epilogue: C/D layout col=lane&15, row=(lane>>4)*4+reg (m89/m91 verified)
#pragma unroll
  for (int mi = 0; mi < 4; mi++) {
#pragma unroll
    for (int ni = 0; ni < 4; ni++) {
#pragma unroll
      for (int r = 0; r < 4; r++) {
        size_t row = arow0 + wm + mi*16 + hi*4 + r;
        size_t col = brow0 + wn + ni*16 + r15;
        size_t idx = row * (size_t)N + col;
        float v = acc[mi][ni][r];
        if (MODE == 0)      outB[idx] = f2b(v);
        else if (MODE == 1) outF[idx] = v + resid[idx];
        else if (MODE == 2) outB[idx] = f2b(0.5f * v * (1.0f + erff(v * 0.70710678118654752f)));
        else                outF[idx] = v + resid[idx];
      }
    }
  }
}

// ---------------- Flash attention (causal), bf16 -----------------------------
// QKV[b*2048+t][3072]: Q at col h*64, K at 1024+h*64, V at 2048+h*64.
// Block: 64 q-rows (4 waves x 16), KBLK=32.
// lK: XOR-swizzled chunks (T2) staged via global_load_lds w/ pre-swizzled src.
// lVt[d][tok]: stride 56 elems (112B = 28 banks, 16B-aligned) -> uniform-bank
//   b128 reads; transpose writes rotated j'=(j+ch)&7 -> bank 28j'+(row>>1),
//   all 32 banks once per step = conflict-free.
// lP: row stride 36 (72B) -> conflict-free scalar writes, 2x b64 reads.
__global__ __launch_bounds__(256) void attn_k(
    const unsigned short* __restrict__ QKV, unsigned short* __restrict__ outB)
{
  const int nwg = gridDim.x;                       // 2048
  int logical = ((int)blockIdx.x & 7) * (nwg >> 3) + ((int)blockIdx.x >> 3);
  int qt = 31 - (logical & 31);                    // longest-first (tail balance)
  int bh = logical >> 5;
  int b = bh >> 4, h = bh & 15;
  const int tid = threadIdx.x, lane = tid & 63, w = tid >> 6;
  const int r15 = lane & 15, hi = lane >> 4;
  const int LD = 3072;
  const size_t rowbase = (size_t)b * 2048;
  const int q0 = qt * 64;
  const int qw = q0 + w * 16;                      // wave strip start

  // Q fragments in registers (row = r15, d = kc*32 + hi*8 + j)
  bf16x8 aq[2];
  {
    const unsigned short* qp = QKV + (rowbase + q0 + w*16 + r15) * LD + h * 64;
    aq[0] = *(const bf16x8*)(qp + hi * 8);
    aq[1] = *(const bf16x8*)(qp + 32 + hi * 8);
  }

  __shared__ __attribute__((aligned(16))) unsigned short lK[32 * 64];
  __shared__ __attribute__((aligned(16))) unsigned short lVt[64 * 56];
  __shared__ __attribute__((aligned(16))) unsigned short lP[4][16 * 36];

  f32x4 y[4];
#pragma unroll
  for (int db = 0; db < 4; db++) y[db] = f32x4{0.f, 0.f, 0.f, 0.f};
  float mrow[4] = {-1e30f, -1e30f, -1e30f, -1e30f};
  float lrow[4] = {0.f, 0.f, 0.f, 0.f};

  const int ktmax_w = (qw + 15) >> 5;              // last tile this wave needs
  const int nkt = (q0 >> 5) + 2;                   // block-uniform loop bound

  // per-lane K staging source: wave w covers rows w*8..w*8+7; lane->(row,ch)
  const int krow_st = w*8 + (lane >> 3);
  const int kch_st  = lane & 7;
  const int kcol_st = (kch_st ^ (krow_st & 7)) * 8; // inverse swizzle (rule 21)

  for (int kt = 0; kt < nkt; kt++) {
    __syncthreads();                               // protect LDS reuse
    // stage K via async global->LDS (linear dest, pre-swizzled source)
    async16(QKV + (rowbase + kt*32 + krow_st) * LD + 1024 + h*64 + kcol_st,
            (char*)lK + (size_t)w * 1024);
    {                                              // stage V^T (rotated writes)
      int row = tid >> 3, ch = tid & 7;            // tok row 0..31, 16B chunk
      const unsigned short* vp = QKV + (rowbase + kt*32 + row) * LD + 2048 + h*64 + ch*8;
      u16x8 vv = *(const u16x8*)vp;
#pragma unroll
      for (int j = 0; j < 8; j++) {
        int jr = (j + ch) & 7;                     // rotation: bank 28*jr+(row>>1)
        lVt[(ch*8 + jr)*56 + row] = vv[jr];
      }
    }
    __syncthreads();

    if (kt <= ktmax_w) {
      // S = Q K^T  (S[q][tok]: col=tok=r15(+tb*16), row=q=hi*4+r)
      f32x4 s[2] = { f32x4{0.f,0.f,0.f,0.f}, f32x4{0.f,0.f,0.f,0.f} };
#pragma unroll
      for (int tb = 0; tb < 2; tb++)
#pragma unroll
        for (int kc = 0; kc < 2; kc++) {
          int krow = tb*16 + r15;
          bf16x8 kf = *(const bf16x8*)&lK[krow*64 + ((kc*4 + hi) ^ (krow & 7))*8];
          s[tb] = __builtin_amdgcn_mfma_f32_16x16x32_bf16(aq[kc], kf, s[tb], 0, 0, 0);
        }

      const bool needmask = (kt*32 + 31 > qw);
      float alpha[4];
      unsigned short* lPw = &lP[w][0];
#pragma unroll
      for (int r = 0; r < 4; r++) {
        int q = qw + hi*4 + r;
        float s0 = s[0][r] * 0.125f, s1 = s[1][r] * 0.125f;
        if (needmask) {
          int t0 = kt*32 + r15;
          if (t0 > q)      s0 = -1e30f;
          if (t0 + 16 > q) s1 = -1e30f;
        }
        float mx = fmaxf(s0, s1);
        mx = fmaxf(mx, __shfl_xor(mx, 1, 64));
        mx = fmaxf(mx, __shfl_xor(mx, 2, 64));
        mx = fmaxf(mx, __shfl_xor(mx, 4, 64));
        mx = fmaxf(mx, __shfl_xor(mx, 8, 64));
        float mnew = fmaxf(mrow[r], mx);
        float p0 = __expf(s0 - mnew), p1 = __expf(s1 - mnew);
        float al = __expf(mrow[r] - mnew);
        float rs = p0 + p1;
        rs += __shfl_xor(rs, 1, 64);
        rs += __shfl_xor(rs, 2, 64);
        rs += __shfl_xor(rs, 4, 64);
        rs += __shfl_xor(rs, 8, 64);
        lrow[r] = lrow[r] * al + rs;
        mrow[r] = mnew;
        alpha[r] = al;
        lPw[(hi*4 + r)*36 + r15]      = f2b(p0);   // stride 36: conflict-free
        lPw[(hi*4 + r)*36 + 16 + r15] = f2b(p1);
      }
#pragma unroll
      for (int db = 0; db < 4; db++)
#pragma unroll
        for (int r = 0; r < 4; r++) y[db][r] *= alpha[r];

      asm volatile("s_waitcnt lgkmcnt(0)" ::: "memory");  // P writes visible (in-wave)
      __builtin_amdgcn_sched_barrier(0);

      // pf: A=P row=q=r15, k=tok=hi*8+e  (2x 8B-aligned b64 loads)
      const unsigned short* pp = &lPw[r15*36 + hi*8];
      union { u16x4 h[2]; bf16x8 v; } pu;
      pu.h[0] = *(const u16x4*)pp;
      pu.h[1] = *(const u16x4*)(pp + 4);
      bf16x8 pf = pu.v;

      // y += P V  (B-frag: vf[e] = V[tok=hi*8+e][d=db*16+r15] from lVt[d][tok])
#pragma unroll
      for (int db = 0; db < 4; db++) {
        bf16x8 vf = *(const bf16x8*)&lVt[(db*16 + r15)*56 + hi*8];
        y[db] = __builtin_amdgcn_mfma_f32_16x16x32_bf16(pf, vf, y[db], 0, 0, 0);
      }
    }
  }

#pragma unroll
  for (int r = 0; r < 4; r++) {
    float inv = 1.0f / lrow[r];
    size_t row = rowbase + q0 + w*16 + hi*4 + r;
#pragma unroll
    for (int db = 0; db < 4; db++)
      outB[row * 1024 + h*64 + db*16 + r15] = f2b(y[db][r] * inv);
  }
}

// ---------------------------------------------------------------------------
extern "C" void kernel_launch(void* const* d_in, const int* in_sizes, int n_in,
                              void* d_out, int out_size, void* d_ws, size_t ws_size,
                              hipStream_t stream) {
  const float* x  = (const float*)d_in[0];
  const float* Wq = (const float*)d_in[1];
  const float* Wk = (const float*)d_in[2];
  const float* Wv = (const float*)d_in[3];
  const float* Wo = (const float*)d_in[4];
  const float* W1 = (const float*)d_in[5];
  const float* W2 = (const float*)d_in[6];
  const float* g1 = (const float*)d_in[7];
  const float* g2 = (const float*)d_in[8];
  float* out = (float*)d_out;                      // fp32 output; also holds x1

  // ws layout (bf16 elems): Wqkv_t[3072*1024] Wo_t[1M] W1_t[4M] W2_t[4M]
  //                         xn[8M] attno[8M] qkv[24M]; hff reuses attno+qkv.
  unsigned short* wQKVt = (unsigned short*)d_ws;
  unsigned short* wOt   = wQKVt + (size_t)3072 * 1024;
  unsigned short* w1t   = wOt   + (size_t)1024 * 1024;
  unsigned short* w2t   = w1t   + (size_t)4096 * 1024;
  unsigned short* xn    = w2t   + (size_t)1024 * 4096;
  unsigned short* attno = xn    + (size_t)8192 * 1024;
  unsigned short* qkv   = attno + (size_t)8192 * 1024;
  unsigned short* hff   = attno;                   // [8192,4096] after attn/proj

  transpose_bf16<<<dim3(32, 32),  256, 0, stream>>>(Wq, wQKVt,                     1024, 1024);
  transpose_bf16<<<dim3(32, 32),  256, 0, stream>>>(Wk, wQKVt + (size_t)1024*1024, 1024, 1024);
  transpose_bf16<<<dim3(32, 32),  256, 0, stream>>>(Wv, wQKVt + (size_t)2048*1024, 1024, 1024);
  transpose_bf16<<<dim3(32, 32),  256, 0, stream>>>(Wo, wOt,                       1024, 1024);
  transpose_bf16<<<dim3(128, 32), 256, 0, stream>>>(W1, w1t,                       1024, 4096);
  transpose_bf16<<<dim3(32, 128), 256, 0, stream>>>(W2, w2t,                       4096, 1024);

  rmsnorm_k<<<8192, 256, 0, stream>>>(x, g1, xn);
  gemm_bt<0><<<64 * 24, 256, 0, stream>>>(xn, wQKVt, nullptr, nullptr, qkv, 3072, 1024);
  attn_k<<<2048, 256, 0, stream>>>(qkv, attno);
  gemm_bt<1><<<64 * 8, 256, 0, stream>>>(attno, wOt, x, out, nullptr, 1024, 1024);
  rmsnorm_k<<<8192, 256, 0, stream>>>(out, g2, xn);
  gemm_bt<2><<<64 * 32, 256, 0, stream>>>(xn, w1t, nullptr, nullptr, hff, 4096, 1024);
  gemm_bt<3><<<64 * 8, 256, 0, stream>>>(hff, w2t, out, out, nullptr, 1024, 4096);
}

// Round 6
// 532.829 us; speedup vs baseline: 1.3251x; 1.2536x over previous
//
#include <hip/hip_runtime.h>
#include <hip/hip_bf16.h>

// ---------------------------------------------------------------------------
// TransformerBlock fused pipeline for MI355X (gfx950).
// x:[4,2048,1024] f32. Residual stream fp32; GEMM/attn compute bf16 MFMA.
// Stages:
//   1) transpose-convert weights f32[K,N] -> bf16[N,K] (QKV packed [3072,1024])
//   2) rmsnorm(x,g1) -> bf16 xn
//   3) QKV = xn @ Wqkv            (gemm_bt MODE 0, bf16 out)
//   4) flash attention            (bf16 out)
//   5) x1 = attn @ Wo + x         (MODE 1, fp32 -> d_out)
//   6) rmsnorm(x1,g2) -> bf16 xn
//   7) h  = gelu(xn @ W1)         (MODE 2, bf16 out)
//   8) out = h @ W2 + x1          (MODE 3, fp32 -> d_out, in-place safe)
// ---------------------------------------------------------------------------

typedef __attribute__((ext_vector_type(8))) short bf16x8;    // MFMA A/B frag
typedef __attribute__((ext_vector_type(4))) float f32x4;     // MFMA C/D frag
typedef __attribute__((ext_vector_type(8))) unsigned short u16x8;
typedef __attribute__((ext_vector_type(4))) unsigned short u16x4;

#define DEV static __device__ __forceinline__

DEV unsigned short f2b(float f){
  __hip_bfloat16 h = __float2bfloat16(f);
  union { __hip_bfloat16 h; unsigned short u; } cv; cv.h = h; return cv.u;
}

// async global->LDS, 16B per lane. LDS dest is wave-uniform base; HW adds lane*16.
DEV void async16(const void* g, void* l){
  __builtin_amdgcn_global_load_lds((__attribute__((address_space(1))) void*)(void*)g,
                                   (__attribute__((address_space(3))) void*)l, 16, 0, 0);
}

// ---------------- transpose + f32->bf16 convert: in[R][C] -> out[C][R] -----
__global__ __launch_bounds__(256) void transpose_bf16(
    const float* __restrict__ in, unsigned short* __restrict__ out, int R, int C)
{
  __shared__ float tile[32][33];
  int c0 = blockIdx.x * 32, r0 = blockIdx.y * 32;
  int tx = threadIdx.x & 31, ty = threadIdx.x >> 5;   // 32 x 8
#pragma unroll
  for (int i = 0; i < 4; i++)
    tile[ty + 8*i][tx] = in[(size_t)(r0 + ty + 8*i) * C + c0 + tx];
  __syncthreads();
#pragma unroll
  for (int i = 0; i < 4; i++)
    out[(size_t)(c0 + ty + 8*i) * R + r0 + tx] = f2b(tile[tx][ty + 8*i]);
}

// ---------------- RMSNorm: f32[row][1024] -> bf16, one block per row -------
__global__ __launch_bounds__(256) void rmsnorm_k(
    const float* __restrict__ x, const float* __restrict__ g,
    unsigned short* __restrict__ out)
{
  int row = blockIdx.x, t = threadIdx.x;
  const float4* xr = (const float4*)(x + (size_t)row * 1024);
  float4 v = xr[t];
  float ss = v.x*v.x + v.y*v.y + v.z*v.z + v.w*v.w;
#pragma unroll
  for (int o = 32; o > 0; o >>= 1) ss += __shfl_xor(ss, o, 64);
  __shared__ float wsum[4];
  int lane = t & 63, wv = t >> 6;
  if (lane == 0) wsum[wv] = ss;
  __syncthreads();
  float inv = rsqrtf((wsum[0]+wsum[1]+wsum[2]+wsum[3]) * (1.0f/1024.0f) + 1e-5f);
  float4 gv = ((const float4*)g)[t];
  u16x4 o;
  o[0] = f2b(v.x * inv * gv.x);
  o[1] = f2b(v.y * inv * gv.y);
  o[2] = f2b(v.z * inv * gv.z);
  o[3] = f2b(v.w * inv * gv.w);
  *(u16x4*)(out + (size_t)row * 1024 + t * 4) = o;
}

// ---------------- GEMM: C[M,N] = A[M,K](bf16) @ Bt[N,K](bf16)^T ------------
// 128x128 tile, BK=64, 4 waves (2x2), each wave 64x64 = 4x4 mfma 16x16x32.
// LDS XOR-swizzled (slot ^= row&7) via pre-swizzled global source (rule 21).
// MODE: 0 = bf16 store; 1 = f32 +resid; 2 = gelu->bf16; 3 = f32 +resid.
template<int MODE>
__global__ __launch_bounds__(256) void gemm_bt(
    const unsigned short* __restrict__ A,
    const unsigned short* __restrict__ Bt,
    const float* __restrict__ resid,
    float* __restrict__ outF,
    unsigned short* __restrict__ outB,
    int N, int K)
{
  __shared__ __attribute__((aligned(16))) unsigned short lA[128*64];
  __shared__ __attribute__((aligned(16))) unsigned short lB[128*64];

  const int nTn = N >> 7;
  const int nwg = gridDim.x;                       // all grids %8 == 0
  int wg = ((int)blockIdx.x & 7) * (nwg >> 3) + ((int)blockIdx.x >> 3);
  const int tm = wg / nTn, tn = wg % nTn;
  const int tid = threadIdx.x;
  const int lane = tid & 63, w = tid >> 6;
  const int r15 = lane & 15, hi = lane >> 4;
  const int wm = (w >> 1) << 6, wn = (w & 1) << 6;

  f32x4 acc[4][4];
#pragma unroll
  for (int i = 0; i < 4; i++)
#pragma unroll
    for (int j = 0; j < 4; j++) acc[i][j] = f32x4{0.f, 0.f, 0.f, 0.f};

  const size_t arow0 = (size_t)tm * 128;
  const size_t brow0 = (size_t)tn * 128;

  for (int k0 = 0; k0 < K; k0 += 64) {
    __syncthreads();                                // prev-tile readers done
#pragma unroll
    for (int i = 0; i < 4; i++) {                   // stage A: 16KB
      int s = (i*4 + w) * 64 + lane;
      int row = s >> 3, sl = s & 7;
      int col = (sl ^ (row & 7)) << 3;              // inverse-swizzled source
      async16(A + (arow0 + row) * K + k0 + col, (char*)lA + (size_t)(i*4 + w) * 1024);
    }
#pragma unroll
    for (int i = 0; i < 4; i++) {                   // stage B: 16KB
      int s = (i*4 + w) * 64 + lane;
      int row = s >> 3, sl = s & 7;
      int col = (sl ^ (row & 7)) << 3;
      async16(Bt + (brow0 + row) * K + k0 + col, (char*)lB + (size_t)(i*4 + w) * 1024);
    }
    __syncthreads();                                // vmcnt drained by compiler

#pragma unroll
    for (int kc = 0; kc < 2; kc++) {
      bf16x8 af[4], bfr[4];
#pragma unroll
      for (int mi = 0; mi < 4; mi++) {
        int row = wm + mi*16 + r15;
        int esl = (kc*4 + hi) ^ (row & 7);          // swizzled read
        af[mi] = *(const bf16x8*)&lA[row*64 + esl*8];
      }
#pragma unroll
      for (int ni = 0; ni < 4; ni++) {
        int row = wn + ni*16 + r15;
        int esl = (kc*4 + hi) ^ (row & 7);
        bfr[ni] = *(const bf16x8*)&lB[row*64 + esl*8];
      }
#pragma unroll
      for (int mi = 0; mi < 4; mi++)
#pragma unroll
        for (int ni = 0; ni < 4; ni++)
          acc[mi][ni] = __builtin_amdgcn_mfma_f32_16x16x32_bf16(
              af[mi], bfr[ni], acc[mi][ni], 0, 0, 0);
    }
  }

  // epilogue: C/D layout col=lane&15, row=(lane>>4)*4+reg (m89/m91 verified)
#pragma unroll
  for (int mi = 0; mi < 4; mi++) {
#pragma unroll
    for (int ni = 0; ni < 4; ni++) {
#pragma unroll
      for (int r = 0; r < 4; r++) {
        size_t row = arow0 + wm + mi*16 + hi*4 + r;
        size_t col = brow0 + wn + ni*16 + r15;
        size_t idx = row * (size_t)N + col;
        float v = acc[mi][ni][r];
        if (MODE == 0)      outB[idx] = f2b(v);
        else if (MODE == 1) outF[idx] = v + resid[idx];
        else if (MODE == 2) outB[idx] = f2b(0.5f * v * (1.0f + erff(v * 0.70710678118654752f)));
        else                outF[idx] = v + resid[idx];
      }
    }
  }
}

// ---------------- Flash attention (causal), bf16 -----------------------------
// QKV[b*2048+t][3072]: Q at col h*64, K at 1024+h*64, V at 2048+h*64.
// Block: 64 q-rows (4 waves x 16), KBLK=64, swapped-operand MFMA:
//   S^T[tok][q] = mfma(K, Q): each q-column's scores live in 4 hi-lanes x 16
//   regs -> row-reduce = 15 local fmax + 2 shfl_xor (16,32) [was 32 shfl].
//   y^T[d][q] = mfma(V^T, P) accumulated over 2 tok-chunks.
// lK: XOR-swizzled chunks staged via global_load_lds w/ pre-swizzled src.
// lVt[d][tok^(d&56)] stride 72: static-index scatter writes, conflict-free
//   (banks 4*((R0>>3)^ch)+(rr>>1) cover all 32); b128 reads uniform-min.
// lP[q][tok^(8*(q&7))]: 4x 8B writes (<=4-way), 2x b128 reads uniform-min.
// Softmax in exp2 domain: raw max (monotone), p=exp2(fma(s,SC,-m2)).
__global__ __launch_bounds__(256) void attn_k(
    const unsigned short* __restrict__ QKV, unsigned short* __restrict__ outB)
{
  const int nwg = gridDim.x;                       // 2048
  int logical = ((int)blockIdx.x & 7) * (nwg >> 3) + ((int)blockIdx.x >> 3);
  int qt = 31 - (logical & 31);                    // longest-first (tail balance)
  int bh = logical >> 5;
  int b = bh >> 4, h = bh & 15;
  const int tid = threadIdx.x, lane = tid & 63, w = tid >> 6;
  const int r15 = lane & 15, hi = lane >> 4;
  const int LD = 3072;
  const size_t rowbase = (size_t)b * 2048;
  const int q0 = qt * 64;
  const int qw = q0 + w * 16;                      // wave strip start
  const int myq = qw + r15;                        // this lane's q (S^T col)

  // Q fragments (B-operand): col=q=r15, k=d=kc*32+hi*8+j
  bf16x8 aq[2];
  {
    const unsigned short* qp = QKV + (rowbase + myq) * LD + h * 64;
    aq[0] = *(const bf16x8*)(qp + hi * 8);
    aq[1] = *(const bf16x8*)(qp + 32 + hi * 8);
  }

  __shared__ __attribute__((aligned(16))) unsigned short lK[64 * 64];
  __shared__ __attribute__((aligned(16))) unsigned short lVt[64 * 72];
  __shared__ __attribute__((aligned(16))) unsigned short lP[4][16 * 64];

  f32x4 y[4];                                      // y^T[d=db*16+hi*4+r][q=r15]
#pragma unroll
  for (int db = 0; db < 4; db++) y[db] = f32x4{0.f, 0.f, 0.f, 0.f};
  float mrow = -1e30f, lrow = 0.f;                 // per-lane (q=r15) state

  const int nkt = qt + 1;                          // all waves run all tiles
  const float SC = 0.18033688011112042f;           // 0.125 * log2(e)

  const int krow0 = w*8 + (lane >> 3);             // staging row (i=0)
  const int kch   = lane & 7;                      // 16B chunk

  for (int kt = 0; kt < nkt; kt++) {
    const int kb = kt * 64;
    __syncthreads();                               // prev-tile readers done
#pragma unroll
    for (int i = 0; i < 2; i++) {                  // stage K: 8KB async
      int row = krow0 + i*32;
      int col = (kch ^ (row & 7)) * 8;             // inverse-swizzled source
      async16(QKV + (rowbase + kb + row) * LD + 1024 + h*64 + col,
              (char*)lK + (size_t)(i*4 + w) * 1024);
    }
#pragma unroll
    for (int i = 0; i < 2; i++) {                  // stage V^T: static-idx scatter
      int row = krow0 + i*32;
      const unsigned short* vp = QKV + (rowbase + kb + row) * LD + 2048 + h*64 + kch*8;
      u16x8 vv = *(const u16x8*)vp;
      int vbase = (kch*8)*72 + (row ^ (kch*8));    // d=kch*8+j -> +j*72
#pragma unroll
      for (int j = 0; j < 8; j++)
        lVt[vbase + j*72] = vv[j];
    }
    __syncthreads();

    // S^T[tok][q] = K Q^T : s[tb] rows tok=tb*16+hi*4+r, col q=r15
    f32x4 s[4];
#pragma unroll
    for (int tb = 0; tb < 4; tb++) s[tb] = f32x4{0.f, 0.f, 0.f, 0.f};
#pragma unroll
    for (int tb = 0; tb < 4; tb++) {
      int krow = tb*16 + r15;
#pragma unroll
      for (int kc = 0; kc < 2; kc++) {
        bf16x8 kf = *(const bf16x8*)&lK[krow*64 + ((kc*4 + hi) ^ (krow & 7))*8];
        s[tb] = __builtin_amdgcn_mfma_f32_16x16x32_bf16(kf, aq[kc], s[tb], 0, 0, 0);
      }
    }

    if (kb + 63 > qw) {                            // wave-uniform: last tile only
#pragma unroll
      for (int tb = 0; tb < 4; tb++)
#pragma unroll
        for (int r = 0; r < 4; r++)
          if (kb + tb*16 + hi*4 + r > myq) s[tb][r] = -1e30f;
    }

    float mx = -1e30f;                             // raw-domain max (monotone)
#pragma unroll
    for (int tb = 0; tb < 4; tb++)
#pragma unroll
      for (int r = 0; r < 4; r++) mx = fmaxf(mx, s[tb][r]);
    mx = fmaxf(mx, __shfl_xor(mx, 16, 64));
    mx = fmaxf(mx, __shfl_xor(mx, 32, 64));
    float mnew = fmaxf(mrow, mx);
    float m2 = mnew * SC;
    float al = __builtin_amdgcn_exp2f(fmaf(mrow, SC, -m2));
    mrow = mnew;

    unsigned short* lPw = &lP[w][0];
    const int prot = 8 * (r15 & 7);                // P row XOR rotation
    float rs = 0.f;
#pragma unroll
    for (int tb = 0; tb < 4; tb++) {
      float p0 = __builtin_amdgcn_exp2f(fmaf(s[tb][0], SC, -m2));
      float p1 = __builtin_amdgcn_exp2f(fmaf(s[tb][1], SC, -m2));
      float p2 = __builtin_amdgcn_exp2f(fmaf(s[tb][2], SC, -m2));
      float p3 = __builtin_amdgcn_exp2f(fmaf(s[tb][3], SC, -m2));
      rs += (p0 + p1) + (p2 + p3);
      u16x4 pk;
      pk[0] = f2b(p0); pk[1] = f2b(p1); pk[2] = f2b(p2); pk[3] = f2b(p3);
      *(u16x4*)&lPw[r15*64 + ((tb*16 + hi*4) ^ prot)] = pk;
    }
    rs += __shfl_xor(rs, 16, 64);
    rs += __shfl_xor(rs, 32, 64);
    lrow = lrow * al + rs;
#pragma unroll
    for (int db = 0; db < 4; db++)
#pragma unroll
      for (int r = 0; r < 4; r++) y[db][r] *= al;

    asm volatile("s_waitcnt lgkmcnt(0)" ::: "memory");  // P writes visible (in-wave)
    __builtin_amdgcn_sched_barrier(0);

    // y^T += V^T P : A=vf (row=d, k=tok), B=pf (k=tok, col=q)
#pragma unroll
    for (int kc2 = 0; kc2 < 2; kc2++) {
      bf16x8 pf = *(const bf16x8*)&lPw[r15*64 + ((kc2*32 + hi*8) ^ prot)];
#pragma unroll
      for (int db = 0; db < 4; db++) {
        int d = db*16 + r15;
        bf16x8 vf = *(const bf16x8*)&lVt[d*72 + ((kc2*32 + hi*8) ^ (d & 56))];
        y[db] = __builtin_amdgcn_mfma_f32_16x16x32_bf16(vf, pf, y[db], 0, 0, 0);
      }
    }
  }

  float inv = 1.0f / lrow;
  const size_t obase = (rowbase + myq) * 1024 + h*64;  // row=q, col=h*64+d
#pragma unroll
  for (int db = 0; db < 4; db++) {
    u16x4 o;
#pragma unroll
    for (int r = 0; r < 4; r++) o[r] = f2b(y[db][r] * inv);
    *(u16x4*)(outB + obase + db*16 + hi*4) = o;
  }
}

// ---------------------------------------------------------------------------
extern "C" void kernel_launch(void* const* d_in, const int* in_sizes, int n_in,
                              void* d_out, int out_size, void* d_ws, size_t ws_size,
                              hipStream_t stream) {
  const float* x  = (const float*)d_in[0];
  const float* Wq = (const float*)d_in[1];
  const float* Wk = (const float*)d_in[2];
  const float* Wv = (const float*)d_in[3];
  const float* Wo = (const float*)d_in[4];
  const float* W1 = (const float*)d_in[5];
  const float* W2 = (const float*)d_in[6];
  const float* g1 = (const float*)d_in[7];
  const float* g2 = (const float*)d_in[8];
  float* out = (float*)d_out;                      // fp32 output; also holds x1

  // ws layout (bf16 elems): Wqkv_t[3072*1024] Wo_t[1M] W1_t[4M] W2_t[4M]
  //                         xn[8M] attno[8M] qkv[24M]; hff reuses attno+qkv.
  unsigned short* wQKVt = (unsigned short*)d_ws;
  unsigned short* wOt   = wQKVt + (size_t)3072 * 1024;
  unsigned short* w1t   = wOt   + (size_t)1024 * 1024;
  unsigned short* w2t   = w1t   + (size_t)4096 * 1024;
  unsigned short* xn    = w2t   + (size_t)1024 * 4096;
  unsigned short* attno = xn    + (size_t)8192 * 1024;
  unsigned short* qkv   = attno + (size_t)8192 * 1024;
  unsigned short* hff   = attno;                   // [8192,4096] after attn/proj

  transpose_bf16<<<dim3(32, 32),  256, 0, stream>>>(Wq, wQKVt,                     1024, 1024);
  transpose_bf16<<<dim3(32, 32),  256, 0, stream>>>(Wk, wQKVt + (size_t)1024*1024, 1024, 1024);
  transpose_bf16<<<dim3(32, 32),  256, 0, stream>>>(Wv, wQKVt + (size_t)2048*1024, 1024, 1024);
  transpose_bf16<<<dim3(32, 32),  256, 0, stream>>>(Wo, wOt,                       1024, 1024);
  transpose_bf16<<<dim3(128, 32), 256, 0, stream>>>(W1, w1t,                       1024, 4096);
  transpose_bf16<<<dim3(32, 128), 256, 0, stream>>>(W2, w2t,                       4096, 1024);

  rmsnorm_k<<<8192, 256, 0, stream>>>(x, g1, xn);
  gemm_bt<0><<<64 * 24, 256, 0, stream>>>(xn, wQKVt, nullptr, nullptr, qkv, 3072, 1024);
  attn_k<<<2048, 256, 0, stream>>>(qkv, attno);
  gemm_bt<1><<<64 * 8, 256, 0, stream>>>(attno, wOt, x, out, nullptr, 1024, 1024);
  rmsnorm_k<<<8192, 256, 0, stream>>>(out, g2, xn);
  gemm_bt<2><<<64 * 32, 256, 0, stream>>>(xn, w1t, nullptr, nullptr, hff, 4096, 1024);
  gemm_bt<3><<<64 * 8, 256, 0, stream>>>(hff, w2t, out, out, nullptr, 1024, 4096);
}

// Round 7
// 532.514 us; speedup vs baseline: 1.3259x; 1.0006x over previous
//
#include <hip/hip_runtime.h>
#include <hip/hip_bf16.h>

// ---------------------------------------------------------------------------
// TransformerBlock fused pipeline for MI355X (gfx950).
// x:[4,2048,1024] f32. Residual stream fp32; GEMM/attn compute bf16 MFMA.
// Stages:
//   1) transpose-convert weights f32[K,N] -> bf16[N,K] (QKV packed [3072,1024])
//   2) rmsnorm(x,g1) -> bf16 xn
//   3) QKV = xn @ Wqkv            (gemm 256x256 MODE 0, bf16 out)
//   4) flash attention            (bf16 out)
//   5) x1 = attn @ Wo + x         (gemm 128x256 MODE 1, fp32 -> d_out)
//   6) rmsnorm(x1,g2) -> bf16 xn
//   7) h  = gelu(xn @ W1)         (gemm 256x256 MODE 2, bf16 out)
//   8) out = h @ W2 + x1          (gemm 128x256 MODE 3, fp32, in-place safe)
// GEMM: 8 waves (2Mx4N), double-buffered LDS, min-2-phase pipeline:
//   stage(t+1) issued BEFORE compute(t); ONE __syncthreads per K-step
//   (compiler drains vmcnt(0)+lgkmcnt(0) at the barrier).
// ---------------------------------------------------------------------------

typedef __attribute__((ext_vector_type(8))) short bf16x8;    // MFMA A/B frag
typedef __attribute__((ext_vector_type(4))) float f32x4;     // MFMA C/D frag
typedef __attribute__((ext_vector_type(8))) unsigned short u16x8;
typedef __attribute__((ext_vector_type(4))) unsigned short u16x4;

#define DEV static __device__ __forceinline__

DEV unsigned short f2b(float f){
  __hip_bfloat16 h = __float2bfloat16(f);
  union { __hip_bfloat16 h; unsigned short u; } cv; cv.h = h; return cv.u;
}

// async global->LDS, 16B per lane. LDS dest is wave-uniform base; HW adds lane*16.
DEV void async16(const void* g, void* l){
  __builtin_amdgcn_global_load_lds((__attribute__((address_space(1))) void*)(void*)g,
                                   (__attribute__((address_space(3))) void*)l, 16, 0, 0);
}

// ---------------- transpose + f32->bf16 convert: in[R][C] -> out[C][R] -----
__global__ __launch_bounds__(256) void transpose_bf16(
    const float* __restrict__ in, unsigned short* __restrict__ out, int R, int C)
{
  __shared__ float tile[32][33];
  int c0 = blockIdx.x * 32, r0 = blockIdx.y * 32;
  int tx = threadIdx.x & 31, ty = threadIdx.x >> 5;   // 32 x 8
#pragma unroll
  for (int i = 0; i < 4; i++)
    tile[ty + 8*i][tx] = in[(size_t)(r0 + ty + 8*i) * C + c0 + tx];
  __syncthreads();
#pragma unroll
  for (int i = 0; i < 4; i++)
    out[(size_t)(c0 + ty + 8*i) * R + r0 + tx] = f2b(tile[tx][ty + 8*i]);
}

// ---------------- RMSNorm: f32[row][1024] -> bf16, one block per row -------
__global__ __launch_bounds__(256) void rmsnorm_k(
    const float* __restrict__ x, const float* __restrict__ g,
    unsigned short* __restrict__ out)
{
  int row = blockIdx.x, t = threadIdx.x;
  const float4* xr = (const float4*)(x + (size_t)row * 1024);
  float4 v = xr[t];
  float ss = v.x*v.x + v.y*v.y + v.z*v.z + v.w*v.w;
#pragma unroll
  for (int o = 32; o > 0; o >>= 1) ss += __shfl_xor(ss, o, 64);
  __shared__ float wsum[4];
  int lane = t & 63, wv = t >> 6;
  if (lane == 0) wsum[wv] = ss;
  __syncthreads();
  float inv = rsqrtf((wsum[0]+wsum[1]+wsum[2]+wsum[3]) * (1.0f/1024.0f) + 1e-5f);
  float4 gv = ((const float4*)g)[t];
  u16x4 o;
  o[0] = f2b(v.x * inv * gv.x);
  o[1] = f2b(v.y * inv * gv.y);
  o[2] = f2b(v.z * inv * gv.z);
  o[3] = f2b(v.w * inv * gv.w);
  *(u16x4*)(out + (size_t)row * 1024 + t * 4) = o;
}

// ---------------- GEMM: C[M,N] = A[M,K](bf16) @ Bt[N,K](bf16)^T ------------
// Tile BM x BN, BK=64. 8 waves (2Mx4N): per-wave BM/2 x 64, MR=BM/32 m-frags.
// Double-buffered LDS; stage(t+1) issued before compute(t); one barrier/step.
// LDS XOR-swizzled (slot ^= row&7) via pre-swizzled global source (rule 21).
// MODE: 0 = bf16 store; 1 = f32 +resid; 2 = gelu->bf16; 3 = f32 +resid.
template<int BM, int BN, int MODE>
__global__ __launch_bounds__(512, 1) void gemm_bt(
    const unsigned short* __restrict__ A,
    const unsigned short* __restrict__ Bt,
    const float* __restrict__ resid,
    float* __restrict__ outF,
    unsigned short* __restrict__ outB,
    int N, int K)
{
  constexpr int MR = BM / 32;                      // m-fragments per wave
  constexpr int NA = BM / 64;                      // A stage issues per wave
  constexpr int NB = BN / 64;                      // B stage issues per wave
  __shared__ __attribute__((aligned(16))) unsigned short lA[2][BM*64];
  __shared__ __attribute__((aligned(16))) unsigned short lB[2][BN*64];

  const int nTn = N / BN;
  const int nwg = gridDim.x;                       // all grids %8 == 0
  int wg = ((int)blockIdx.x & 7) * (nwg >> 3) + ((int)blockIdx.x >> 3);
  const int tm = wg / nTn, tn = wg % nTn;
  const int tid = threadIdx.x;
  const int lane = tid & 63, w = tid >> 6;         // 8 waves
  const int r15 = lane & 15, hi = lane >> 4;
  const int wm = (w >> 2) * (BM/2), wn = (w & 3) * 64;

  f32x4 acc[MR][4];
#pragma unroll
  for (int i = 0; i < MR; i++)
#pragma unroll
    for (int j = 0; j < 4; j++) acc[i][j] = f32x4{0.f, 0.f, 0.f, 0.f};

  const size_t arow0 = (size_t)tm * BM;
  const size_t brow0 = (size_t)tn * BN;
  const int srow = lane >> 3, sch = lane & 7;      // staging: 8 rows x 8 chunks

  auto stage = [&](int buf, int k0) {
#pragma unroll
    for (int i = 0; i < NA; i++) {                 // A: NA KB per wave
      int slot = i*8 + w;
      int row = slot*8 + srow;
      int col = (sch ^ (row & 7)) << 3;            // inverse-swizzled source
      async16(A + (arow0 + row) * K + k0 + col,
              (char*)&lA[buf][0] + (size_t)slot * 1024);
    }
#pragma unroll
    for (int i = 0; i < NB; i++) {                 // B
      int slot = i*8 + w;
      int row = slot*8 + srow;
      int col = (sch ^ (row & 7)) << 3;
      async16(Bt + (brow0 + row) * K + k0 + col,
              (char*)&lB[buf][0] + (size_t)slot * 1024);
    }
  };

  int cur = 0;
  stage(0, 0);
  __syncthreads();                                 // drain vmcnt(0): buf0 ready

  for (int k0 = 0; k0 < K; k0 += 64) {
    if (k0 + 64 < K) stage(cur ^ 1, k0 + 64);      // issue next tile (no wait)

#pragma unroll
    for (int kc = 0; kc < 2; kc++) {
      bf16x8 bfr[4];
#pragma unroll
      for (int ni = 0; ni < 4; ni++) {
        int row = wn + ni*16 + r15;
        bfr[ni] = *(const bf16x8*)&lB[cur][row*64 + (((kc*4 + hi) ^ (row & 7)) << 3)];
      }
#pragma unroll
      for (int mi = 0; mi < MR; mi++) {
        int row = wm + mi*16 + r15;
        bf16x8 af = *(const bf16x8*)&lA[cur][row*64 + (((kc*4 + hi) ^ (row & 7)) << 3)];
#pragma unroll
        for (int ni = 0; ni < 4; ni++)
          acc[mi][ni] = __builtin_amdgcn_mfma_f32_16x16x32_bf16(
              af, bfr[ni], acc[mi][ni], 0, 0, 0);
      }
    }
    __syncthreads();     // readers of buf[cur] done + stage into buf[cur^1] drained
    cur ^= 1;
  }

  // epilogue: C/D layout col=lane&15, row=(lane>>4)*4+reg (m89/m91 verified)
#pragma unroll
  for (int mi = 0; mi < MR; mi++) {
#pragma unroll
    for (int ni = 0; ni < 4; ni++) {
#pragma unroll
      for (int r = 0; r < 4; r++) {
        size_t row = arow0 + wm + mi*16 + hi*4 + r;
        size_t col = brow0 + wn + ni*16 + r15;
        size_t idx = row * (size_t)N + col;
        float v = acc[mi][ni][r];
        if (MODE == 0)      outB[idx] = f2b(v);
        else if (MODE == 1) outF[idx] = v + resid[idx];
        else if (MODE == 2) outB[idx] = f2b(0.5f * v * (1.0f + erff(v * 0.70710678118654752f)));
        else                outF[idx] = v + resid[idx];
      }
    }
  }
}

// ---------------- Flash attention (causal), bf16 -----------------------------
// QKV[b*2048+t][3072]: Q at col h*64, K at 1024+h*64, V at 2048+h*64.
// Block: 64 q-rows (4 waves x 16), KBLK=64, swapped-operand MFMA:
//   S^T[tok][q] = mfma(K, Q); y^T[d][q] = mfma(V^T, P).
// lK: XOR-swizzled chunks staged via global_load_lds w/ pre-swizzled src.
// lVt[d][tok^(d&56)] stride 72: static-index scatter writes, conflict-free.
// lP[q][tok^(8*(q&7))]: 4x 8B writes (<=4-way), 2x b128 reads uniform-min.
// Softmax in exp2 domain: raw max (monotone), p=exp2(fma(s,SC,-m2)).
__global__ __launch_bounds__(256) void attn_k(
    const unsigned short* __restrict__ QKV, unsigned short* __restrict__ outB)
{
  const int nwg = gridDim.x;                       // 2048
  int logical = ((int)blockIdx.x & 7) * (nwg >> 3) + ((int)blockIdx.x >> 3);
  int qt = 31 - (logical & 31);                    // longest-first (tail balance)
  int bh = logical >> 5;
  int b = bh >> 4, h = bh & 15;
  const int tid = threadIdx.x, lane = tid & 63, w = tid >> 6;
  const int r15 = lane & 15, hi = lane >> 4;
  const int LD = 3072;
  const size_t rowbase = (size_t)b * 2048;
  const int q0 = qt * 64;
  const int qw = q0 + w * 16;                      // wave strip start
  const int myq = qw + r15;                        // this lane's q (S^T col)

  // Q fragments (B-operand): col=q=r15, k=d=kc*32+hi*8+j
  bf16x8 aq[2];
  {
    const unsigned short* qp = QKV + (rowbase + myq) * LD + h * 64;
    aq[0] = *(const bf16x8*)(qp + hi * 8);
    aq[1] = *(const bf16x8*)(qp + 32 + hi * 8);
  }

  __shared__ __attribute__((aligned(16))) unsigned short lK[64 * 64];
  __shared__ __attribute__((aligned(16))) unsigned short lVt[64 * 72];
  __shared__ __attribute__((aligned(16))) unsigned short lP[4][16 * 64];

  f32x4 y[4];                                      // y^T[d=db*16+hi*4+r][q=r15]
#pragma unroll
  for (int db = 0; db < 4; db++) y[db] = f32x4{0.f, 0.f, 0.f, 0.f};
  float mrow = -1e30f, lrow = 0.f;                 // per-lane (q=r15) state

  const int nkt = qt + 1;                          // all waves run all tiles
  const float SC = 0.18033688011112042f;           // 0.125 * log2(e)

  const int krow0 = w*8 + (lane >> 3);             // staging row (i=0)
  const int kch   = lane & 7;                      // 16B chunk

  for (int kt = 0; kt < nkt; kt++) {
    const int kb = kt * 64;
    __syncthreads();                               // prev-tile readers done
#pragma unroll
    for (int i = 0; i < 2; i++) {                  // stage K: 8KB async
      int row = krow0 + i*32;
      int col = (kch ^ (row & 7)) * 8;             // inverse-swizzled source
      async16(QKV + (rowbase + kb + row) * LD + 1024 + h*64 + col,
              (char*)lK + (size_t)(i*4 + w) * 1024);
    }
#pragma unroll
    for (int i = 0; i < 2; i++) {                  // stage V^T: static-idx scatter
      int row = krow0 + i*32;
      const unsigned short* vp = QKV + (rowbase + kb + row) * LD + 2048 + h*64 + kch*8;
      u16x8 vv = *(const u16x8*)vp;
      int vbase = (kch*8)*72 + (row ^ (kch*8));    // d=kch*8+j -> +j*72
#pragma unroll
      for (int j = 0; j < 8; j++)
        lVt[vbase + j*72] = vv[j];
    }
    __syncthreads();

    // S^T[tok][q] = K Q^T : s[tb] rows tok=tb*16+hi*4+r, col q=r15
    f32x4 s[4];
#pragma unroll
    for (int tb = 0; tb < 4; tb++) s[tb] = f32x4{0.f, 0.f, 0.f, 0.f};
#pragma unroll
    for (int tb = 0; tb < 4; tb++) {
      int krow = tb*16 + r15;
#pragma unroll
      for (int kc = 0; kc < 2; kc++) {
        bf16x8 kf = *(const bf16x8*)&lK[krow*64 + ((kc*4 + hi) ^ (krow & 7))*8];
        s[tb] = __builtin_amdgcn_mfma_f32_16x16x32_bf16(kf, aq[kc], s[tb], 0, 0, 0);
      }
    }

    if (kb + 63 > qw) {                            // wave-uniform: last tile only
#pragma unroll
      for (int tb = 0; tb < 4; tb++)
#pragma unroll
        for (int r = 0; r < 4; r++)
          if (kb + tb*16 + hi*4 + r > myq) s[tb][r] = -1e30f;
    }

    float mx = -1e30f;                             // raw-domain max (monotone)
#pragma unroll
    for (int tb = 0; tb < 4; tb++)
#pragma unroll
      for (int r = 0; r < 4; r++) mx = fmaxf(mx, s[tb][r]);
    mx = fmaxf(mx, __shfl_xor(mx, 16, 64));
    mx = fmaxf(mx, __shfl_xor(mx, 32, 64));
    float mnew = fmaxf(mrow, mx);
    float m2 = mnew * SC;
    float al = __builtin_amdgcn_exp2f(fmaf(mrow, SC, -m2));
    mrow = mnew;

    unsigned short* lPw = &lP[w][0];
    const int prot = 8 * (r15 & 7);                // P row XOR rotation
    float rs = 0.f;
#pragma unroll
    for (int tb = 0; tb < 4; tb++) {
      float p0 = __builtin_amdgcn_exp2f(fmaf(s[tb][0], SC, -m2));
      float p1 = __builtin_amdgcn_exp2f(fmaf(s[tb][1], SC, -m2));
      float p2 = __builtin_amdgcn_exp2f(fmaf(s[tb][2], SC, -m2));
      float p3 = __builtin_amdgcn_exp2f(fmaf(s[tb][3], SC, -m2));
      rs += (p0 + p1) + (p2 + p3);
      u16x4 pk;
      pk[0] = f2b(p0); pk[1] = f2b(p1); pk[2] = f2b(p2); pk[3] = f2b(p3);
      *(u16x4*)&lPw[r15*64 + ((tb*16 + hi*4) ^ prot)] = pk;
    }
    rs += __shfl_xor(rs, 16, 64);
    rs += __shfl_xor(rs, 32, 64);
    lrow = lrow * al + rs;
#pragma unroll
    for (int db = 0; db < 4; db++)
#pragma unroll
      for (int r = 0; r < 4; r++) y[db][r] *= al;

    asm volatile("s_waitcnt lgkmcnt(0)" ::: "memory");  // P writes visible (in-wave)
    __builtin_amdgcn_sched_barrier(0);

    // y^T += V^T P : A=vf (row=d, k=tok), B=pf (k=tok, col=q)
#pragma unroll
    for (int kc2 = 0; kc2 < 2; kc2++) {
      bf16x8 pf = *(const bf16x8*)&lPw[r15*64 + ((kc2*32 + hi*8) ^ prot)];
#pragma unroll
      for (int db = 0; db < 4; db++) {
        int d = db*16 + r15;
        bf16x8 vf = *(const bf16x8*)&lVt[d*72 + ((kc2*32 + hi*8) ^ (d & 56))];
        y[db] = __builtin_amdgcn_mfma_f32_16x16x32_bf16(vf, pf, y[db], 0, 0, 0);
      }
    }
  }

  float inv = 1.0f / lrow;
  const size_t obase = (rowbase + myq) * 1024 + h*64;  // row=q, col=h*64+d
#pragma unroll
  for (int db = 0; db < 4; db++) {
    u16x4 o;
#pragma unroll
    for (int r = 0; r < 4; r++) o[r] = f2b(y[db][r] * inv);
    *(u16x4*)(outB + obase + db*16 + hi*4) = o;
  }
}

// ---------------------------------------------------------------------------
extern "C" void kernel_launch(void* const* d_in, const int* in_sizes, int n_in,
                              void* d_out, int out_size, void* d_ws, size_t ws_size,
                              hipStream_t stream) {
  const float* x  = (const float*)d_in[0];
  const float* Wq = (const float*)d_in[1];
  const float* Wk = (const float*)d_in[2];
  const float* Wv = (const float*)d_in[3];
  const float* Wo = (const float*)d_in[4];
  const float* W1 = (const float*)d_in[5];
  const float* W2 = (const float*)d_in[6];
  const float* g1 = (const float*)d_in[7];
  const float* g2 = (const float*)d_in[8];
  float* out = (float*)d_out;                      // fp32 output; also holds x1

  // ws layout (bf16 elems): Wqkv_t[3072*1024] Wo_t[1M] W1_t[4M] W2_t[4M]
  //                         xn[8M] attno[8M] qkv[24M]; hff reuses attno+qkv.
  unsigned short* wQKVt = (unsigned short*)d_ws;
  unsigned short* wOt   = wQKVt + (size_t)3072 * 1024;
  unsigned short* w1t   = wOt   + (size_t)1024 * 1024;
  unsigned short* w2t   = w1t   + (size_t)4096 * 1024;
  unsigned short* xn    = w2t   + (size_t)1024 * 4096;
  unsigned short* attno = xn    + (size_t)8192 * 1024;
  unsigned short* qkv   = attno + (size_t)8192 * 1024;
  unsigned short* hff   = attno;                   // [8192,4096] after attn/proj

  transpose_bf16<<<dim3(32, 32),  256, 0, stream>>>(Wq, wQKVt,                     1024, 1024);
  transpose_bf16<<<dim3(32, 32),  256, 0, stream>>>(Wk, wQKVt + (size_t)1024*1024, 1024, 1024);
  transpose_bf16<<<dim3(32, 32),  256, 0, stream>>>(Wv, wQKVt + (size_t)2048*1024, 1024, 1024);
  transpose_bf16<<<dim3(32, 32),  256, 0, stream>>>(Wo, wOt,                       1024, 1024);
  transpose_bf16<<<dim3(128, 32), 256, 0, stream>>>(W1, w1t,                       1024, 4096);
  transpose_bf16<<<dim3(32, 128), 256, 0, stream>>>(W2, w2t,                       4096, 1024);

  rmsnorm_k<<<8192, 256, 0, stream>>>(x, g1, xn);
  gemm_bt<256,256,0><<<32 * 12, 512, 0, stream>>>(xn, wQKVt, nullptr, nullptr, qkv, 3072, 1024);
  attn_k<<<2048, 256, 0, stream>>>(qkv, attno);
  gemm_bt<128,256,1><<<64 * 4, 512, 0, stream>>>(attno, wOt, x, out, nullptr, 1024, 1024);
  rmsnorm_k<<<8192, 256, 0, stream>>>(out, g2, xn);
  gemm_bt<256,256,2><<<32 * 16, 512, 0, stream>>>(xn, w1t, nullptr, nullptr, hff, 4096, 1024);
  gemm_bt<128,256,3><<<64 * 4, 512, 0, stream>>>(hff, w2t, out, out, nullptr, 1024, 4096);
}